// Round 4
// baseline (1144.484 us; speedup 1.0000x reference)
//
#include <hip/hip_runtime.h>
#include <hip/hip_bf16.h>

#define DIM 512
#define HID 2048
#define MT  64
#define KS1 8     // 512/64  k-steps GEMM1 (i8 K=64)
#define KS2 32    // 2048/64 k-steps GEMM2

typedef __attribute__((ext_vector_type(4))) int      i32x4;
typedef __attribute__((ext_vector_type(4))) unsigned u32x4;

static __device__ __forceinline__ unsigned short f2bf(float f) {
  __hip_bfloat16 b = __float2bfloat16(f);   // RNE
  unsigned short s;
  __builtin_memcpy(&s, &b, 2);
  return s;
}
static __device__ __forceinline__ float bf2f(unsigned short u) {
  unsigned v = ((unsigned)u) << 16;
  float f;
  __builtin_memcpy(&f, &v, 4);
  return f;
}

// branch-free exact-erf GELU via Abramowitz-Stegun 7.1.26 (abs err 1.5e-7)
static __device__ __forceinline__ float gelu_erf(float h) {
  const float u  = h * 0.70710678118654752f;
  const float au = fabsf(u);
  const float t  = __builtin_amdgcn_rcpf(fmaf(0.3275911f, au, 1.f));
  float p = fmaf(1.061405429f, t, -1.453152027f);
  p = fmaf(p, t, 1.421413741f);
  p = fmaf(p, t, -0.284496736f);
  p = fmaf(p, t, 0.254829592f);
  p *= t;
  const float e  = __builtin_amdgcn_exp2f(-u * u * 1.4426950408889634f);  // exp(-u^2)
  const float ea = fmaf(-p, e, 1.f);                                      // erf(|u|)
  const float er = __builtin_copysignf(ea, u);
  return fmaf(0.5f * h, er, 0.5f * h);
}

static __device__ __forceinline__ unsigned q4pack(float4 v, float scl) {
  int q0 = (int)fminf(fmaxf(rintf(v.x * scl), -128.f), 127.f);
  int q1 = (int)fminf(fmaxf(rintf(v.y * scl), -128.f), 127.f);
  int q2 = (int)fminf(fmaxf(rintf(v.z * scl), -128.f), 127.f);
  int q3 = (int)fminf(fmaxf(rintf(v.w * scl), -128.f), 127.f);
  return (unsigned)(q0 & 255) | ((unsigned)(q1 & 255) << 8) |
         ((unsigned)(q2 & 255) << 16) | ((unsigned)(q3 & 255) << 24);
}

// ---------------- K0a: per-block partial sums of |w| ----------------
__global__ void k_wabs(const float* __restrict__ w1, const float* __restrict__ w2,
                       float* __restrict__ part) {
  const int b = blockIdx.x;
  const float* src = (b < 256 ? w1 : w2) + (size_t)(b & 255) * 4096 + threadIdx.x * 16;
  float s = 0.f;
#pragma unroll
  for (int i = 0; i < 4; ++i) {
    float4 v = *(const float4*)(src + i * 4);
    s += fabsf(v.x) + fabsf(v.y) + fabsf(v.z) + fabsf(v.w);
  }
  __shared__ float red[256];
  red[threadIdx.x] = s;
  __syncthreads();
  for (int off = 128; off > 0; off >>= 1) {
    if (threadIdx.x < (unsigned)off) red[threadIdx.x] += red[threadIdx.x + off];
    __syncthreads();
  }
  if (threadIdx.x == 0) part[b] = red[0];
}

// ---------------- K0b: final mean-abs -> scales ----------------
__global__ void k_wscale(const float* __restrict__ part, float* __restrict__ scales) {
  __shared__ float s1[256], s2[256];
  s1[threadIdx.x] = part[threadIdx.x];
  s2[threadIdx.x] = part[256 + threadIdx.x];
  __syncthreads();
  for (int off = 128; off > 0; off >>= 1) {
    if (threadIdx.x < (unsigned)off) {
      s1[threadIdx.x] += s1[threadIdx.x + off];
      s2[threadIdx.x] += s2[threadIdx.x + off];
    }
    __syncthreads();
  }
  if (threadIdx.x == 0) {
    const float mc1 = fmaxf(s1[0] / 1048576.f, 1e-5f);
    const float mc2 = fmaxf(s2[0] / 1048576.f, 1e-5f);
    scales[0] = mc1; scales[1] = 1.f / mc1;
    scales[2] = mc2; scales[3] = 1.f / mc2;
  }
}

// ---------------- K1: ternary-quantize weights, pack i8 MFMA fragments ----
// frag (nt,ks): lane l holds w[nt*16+(l&15)][ks*64+(l>>4)*16 + j], j=0..15
__global__ void k_pack(const float* __restrict__ w1, const float* __restrict__ w2,
                       const float* __restrict__ scales,
                       signed char* __restrict__ p1, signed char* __restrict__ p2) {
  int slot = blockIdx.x * 256 + threadIdx.x;    // 0..131071 (first 65536 -> p1)
  const bool isw2 = slot >= 65536;
  const float* w = isw2 ? w2 : w1;
  const float scl = isw2 ? scales[3] : scales[1];
  signed char* p = isw2 ? p2 : p1;
  const int K  = isw2 ? HID : DIM;
  const int KS = isw2 ? KS2 : KS1;
  slot &= 65535;
  const int lane = slot & 63;
  const int fr   = slot >> 6;
  const int nt   = fr / KS;
  const int ks   = fr - nt * KS;
  const int n  = nt * 16 + (lane & 15);
  const int k0 = ks * 64 + (lane >> 4) * 16;
  const float* src = w + (size_t)n * K + k0;
  i32x4 outv;
#pragma unroll
  for (int d = 0; d < 4; ++d) {
    unsigned v = 0;
#pragma unroll
    for (int e = 0; e < 4; ++e) {
      int q = (int)fminf(fmaxf(rintf(src[d * 4 + e] * scl), -1.f), 1.f);
      v |= ((unsigned)(q & 255)) << (8 * e);
    }
    outv[d] = (int)v;
  }
  *(i32x4*)(p + (size_t)slot * 16) = outv;
}

// ---------------- K2: fused quant -> GEMM1(i8) -> GELU -> quant -> GEMM2(i8) -> residual
// MT=64 tokens/block, 8 waves, LDS = 32KB xq + 128KB qh = 160KiB exactly.
__global__ __launch_bounds__(512, 2) void k_fused(
    const float* __restrict__ x, const float* __restrict__ b1,
    const float* __restrict__ b2, const signed char* __restrict__ p1,
    const signed char* __restrict__ p2, const float* __restrict__ scales,
    float* __restrict__ out) {
  __shared__ __align__(16) signed char qh[MT * HID];   // 128 KB (i8 h, swizzled)
  __shared__ __align__(16) signed char xq[MT * DIM];   // 32 KB  (i8 x, swizzled)

  // LDS aliases into dead regions:
  float* rxTab = (float*)qh;           // [64] recip_x*wsc1 — live phase1..end GEMM1
  float* scrP  = (float*)xq;           // [8][64] rowmax partials — live after GEMM1
  float* scrS  = scrP + 512;           // [64] 127/mc
  float* scrR  = scrP + 576;           // [64] (mc/127)*wsc2

  const int tid = threadIdx.x;
  const int wv = tid >> 6, ln = tid & 63, lg = ln >> 4, lr = ln & 15;
  const int tok0 = blockIdx.x * MT;
  const float wsc1 = scales[0], wsc2 = scales[2];
  const int swz = (lr & 7) << 4;       // A-row swizzle: row&7 == lr&7 for row=mt*16+lr

  // ---- phase 1: load x, per-token absmax int8 quant -> xq (swizzled)
  {
    const int row = tid >> 3, sub = tid & 7;       // 8 threads per 512-float row
    const float4* xr = (const float4*)(x + (size_t)(tok0 + row) * DIM) + sub * 16;
    float4 v[16];
    float am = 0.f;
#pragma unroll
    for (int i = 0; i < 16; ++i) {
      v[i] = xr[i];
      am = fmaxf(am, fmaxf(fmaxf(fabsf(v[i].x), fabsf(v[i].y)),
                           fmaxf(fabsf(v[i].z), fabsf(v[i].w))));
    }
#pragma unroll
    for (int m = 1; m < 8; m <<= 1) am = fmaxf(am, __shfl_xor(am, m));
    const float mc  = fmaxf(am, 1e-5f);
    const float scl = 127.f / mc;
    if (sub == 0) rxTab[row] = mc * (1.f / 127.f) * wsc1;
    const int rswz = (row & 7) << 4;
#pragma unroll
    for (int g16 = 0; g16 < 4; ++g16) {
      u32x4 u;
#pragma unroll
      for (int e = 0; e < 4; ++e) u[e] = q4pack(v[g16 * 4 + e], scl);
      *(u32x4*)&xq[row * DIM + ((sub * 64 + g16 * 16) ^ rswz)] = u;
    }
  }
  __syncthreads();

  float rxw[4][4];
#pragma unroll
  for (int mt = 0; mt < 4; ++mt)
#pragma unroll
    for (int r = 0; r < 4; ++r) rxw[mt][r] = rxTab[mt * 16 + lg * 4 + r];

  // ---- GEMM1: [64 x 2048] i8; wave owns 16 n-tiles in 4 chunks of 4; g -> regs (bf16)
  unsigned gpack[4][4][4][2];          // [ch][t][mt][pr] packed 2x bf16
  float hmax[4][4];
#pragma unroll
  for (int mt = 0; mt < 4; ++mt)
#pragma unroll
    for (int r = 0; r < 4; ++r) hmax[mt][r] = 0.f;

#pragma unroll
  for (int ch = 0; ch < 4; ++ch) {
    i32x4 acc[4][4];
#pragma unroll
    for (int t = 0; t < 4; ++t)
#pragma unroll
      for (int mt = 0; mt < 4; ++mt) acc[t][mt] = (i32x4){0, 0, 0, 0};
#pragma unroll
    for (int ks = 0; ks < KS1; ++ks) {
      i32x4 a[4];
#pragma unroll
      for (int mt = 0; mt < 4; ++mt)
        a[mt] = *(const i32x4*)&xq[(mt * 16 + lr) * DIM + ((ks * 64 + lg * 16) ^ swz)];
#pragma unroll
      for (int t = 0; t < 4; ++t) {
        const int nt = wv * 16 + ch * 4 + t;
        const i32x4 bfr = *(const i32x4*)(p1 + ((size_t)(nt * KS1 + ks) * 64 + ln) * 16);
#pragma unroll
        for (int mt = 0; mt < 4; ++mt)
          acc[t][mt] = __builtin_amdgcn_mfma_i32_16x16x64_i8(a[mt], bfr, acc[t][mt], 0, 0, 0);
      }
    }
    // chunk epilogue: h = acc*rx + b1 ; GELU ; pack bf16 ; track row |max|
#pragma unroll
    for (int t = 0; t < 4; ++t) {
      const int col = (wv * 16 + ch * 4 + t) * 16 + lr;
      const float bias = b1[col];
#pragma unroll
      for (int mt = 0; mt < 4; ++mt) {
#pragma unroll
        for (int pr = 0; pr < 2; ++pr) {
          unsigned v = 0;
#pragma unroll
          for (int hf = 0; hf < 2; ++hf) {
            const int r = pr * 2 + hf;
            const float hv = fmaf((float)acc[t][mt][r], rxw[mt][r], bias);
            const float g  = gelu_erf(hv);
            hmax[mt][r] = fmaxf(hmax[mt][r], fabsf(g));
            v |= ((unsigned)f2bf(g)) << (16 * hf);
          }
          gpack[ch][t][mt][pr] = v;
        }
      }
    }
  }
  __syncthreads();   // xq + rxTab reads complete -> both regions reusable

  // ---- per-token max across waves (16 lanes of each lg-group share rows)
#pragma unroll
  for (int m = 1; m < 16; m <<= 1)
#pragma unroll
    for (int mt = 0; mt < 4; ++mt)
#pragma unroll
      for (int r = 0; r < 4; ++r)
        hmax[mt][r] = fmaxf(hmax[mt][r], __shfl_xor(hmax[mt][r], m));
  if (lr == 0) {
#pragma unroll
    for (int mt = 0; mt < 4; ++mt)
#pragma unroll
      for (int r = 0; r < 4; ++r)
        scrP[wv * 64 + mt * 16 + lg * 4 + r] = hmax[mt][r];
  }
  __syncthreads();
  if (tid < MT) {
    float m = scrP[tid];
#pragma unroll
    for (int w = 1; w < 8; ++w) m = fmaxf(m, scrP[w * 64 + tid]);
    const float mc = fmaxf(m, 1e-5f);
    scrS[tid] = 127.f / mc;
    scrR[tid] = mc * (1.f / 127.f) * wsc2;
  }
  __syncthreads();

  // ---- quantize g (regs) -> qh i8 (swizzled); overwrites rxTab region too (dead)
  {
    float s2w[4][4];
#pragma unroll
    for (int mt = 0; mt < 4; ++mt)
#pragma unroll
      for (int r = 0; r < 4; ++r) s2w[mt][r] = scrS[mt * 16 + lg * 4 + r];
#pragma unroll
    for (int ch = 0; ch < 4; ++ch)
#pragma unroll
      for (int t = 0; t < 4; ++t) {
        const int col = (wv * 16 + ch * 4 + t) * 16 + lr;
#pragma unroll
        for (int mt = 0; mt < 4; ++mt)
#pragma unroll
          for (int pr = 0; pr < 2; ++pr) {
            const unsigned v = gpack[ch][t][mt][pr];
#pragma unroll
            for (int hf = 0; hf < 2; ++hf) {
              const int r = pr * 2 + hf;
              const int row = mt * 16 + lg * 4 + r;
              const float g = bf2f((unsigned short)(hf ? (v >> 16) : (v & 0xffff)));
              const int q = (int)fminf(fmaxf(rintf(g * s2w[mt][r]), -128.f), 127.f);
              qh[row * HID + (col ^ ((row & 7) << 4))] = (signed char)q;
            }
          }
      }
  }
  __syncthreads();

  // ---- GEMM2: [64 x 512] i8; wave owns 4 n-tiles
  i32x4 acc2[4][4];
#pragma unroll
  for (int t = 0; t < 4; ++t)
#pragma unroll
    for (int mt = 0; mt < 4; ++mt) acc2[t][mt] = (i32x4){0, 0, 0, 0};
#pragma unroll 8
  for (int ks = 0; ks < KS2; ++ks) {
    i32x4 a[4];
#pragma unroll
    for (int mt = 0; mt < 4; ++mt)
      a[mt] = *(const i32x4*)&qh[(mt * 16 + lr) * HID + ((ks * 64 + lg * 16) ^ swz)];
#pragma unroll
    for (int t = 0; t < 4; ++t) {
      const int nt = wv * 4 + t;
      const i32x4 bfr = *(const i32x4*)(p2 + ((size_t)(nt * KS2 + ks) * 64 + ln) * 16);
#pragma unroll
      for (int mt = 0; mt < 4; ++mt)
        acc2[t][mt] = __builtin_amdgcn_mfma_i32_16x16x64_i8(a[mt], bfr, acc2[t][mt], 0, 0, 0);
    }
  }
  float r2w[4][4];
#pragma unroll
  for (int mt = 0; mt < 4; ++mt)
#pragma unroll
    for (int r = 0; r < 4; ++r) r2w[mt][r] = scrR[mt * 16 + lg * 4 + r];
#pragma unroll
  for (int t = 0; t < 4; ++t) {
    const int col = (wv * 4 + t) * 16 + lr;
    const float bias = b2[col];
#pragma unroll
    for (int mt = 0; mt < 4; ++mt) {
#pragma unroll
      for (int r = 0; r < 4; ++r) {
        const int row = mt * 16 + lg * 4 + r;
        const size_t gidx = (size_t)(tok0 + row) * DIM + col;
        out[gidx] = fmaf((float)acc2[t][mt][r], r2w[mt][r], bias) + x[gidx];
      }
    }
  }
}

extern "C" void kernel_launch(void* const* d_in, const int* in_sizes, int n_in,
                              void* d_out, int out_size, void* d_ws, size_t ws_size,
                              hipStream_t stream) {
  const float* x  = (const float*)d_in[0];
  const float* w1 = (const float*)d_in[1];
  const float* b1 = (const float*)d_in[2];
  const float* w2 = (const float*)d_in[3];
  const float* b2 = (const float*)d_in[4];
  float* out = (float*)d_out;

  float* wpart   = (float*)d_ws;
  float* wscales = wpart + 512;
  signed char* p1 = (signed char*)((char*)d_ws + 4096);
  signed char* p2 = (signed char*)((char*)d_ws + 4096 + 1048576);

  k_wabs<<<512, 256, 0, stream>>>(w1, w2, wpart);
  k_wscale<<<1, 256, 0, stream>>>(wpart, wscales);
  k_pack<<<512, 256, 0, stream>>>(w1, w2, wscales, p1, p2);
  k_fused<<<1024, 512, 0, stream>>>(x, b1, b2, p1, p2, wscales, out);
}

// Round 5
// 565.280 us; speedup vs baseline: 2.0246x; 2.0246x over previous
//
#include <hip/hip_runtime.h>
#include <hip/hip_bf16.h>

#define DIM 512
#define HID 2048
#define MT  64
#define KS1 8     // 512/64  k-steps GEMM1 (i8 K=64)
#define KS2 32    // 2048/64 k-steps GEMM2

typedef __attribute__((ext_vector_type(4))) int      i32x4;
typedef __attribute__((ext_vector_type(4))) unsigned u32x4;
typedef __attribute__((ext_vector_type(2))) unsigned u32x2;

static __device__ __forceinline__ unsigned short f2bf(float f) {
  __hip_bfloat16 b = __float2bfloat16(f);   // RNE
  unsigned short s;
  __builtin_memcpy(&s, &b, 2);
  return s;
}
static __device__ __forceinline__ float bf2f(unsigned short u) {
  unsigned v = ((unsigned)u) << 16;
  float f;
  __builtin_memcpy(&f, &v, 4);
  return f;
}

// branch-free exact-erf GELU via Abramowitz-Stegun 7.1.26 (abs err 1.5e-7)
static __device__ __forceinline__ float gelu_erf(float h) {
  const float u  = h * 0.70710678118654752f;
  const float au = fabsf(u);
  const float t  = __builtin_amdgcn_rcpf(fmaf(0.3275911f, au, 1.f));
  float p = fmaf(1.061405429f, t, -1.453152027f);
  p = fmaf(p, t, 1.421413741f);
  p = fmaf(p, t, -0.284496736f);
  p = fmaf(p, t, 0.254829592f);
  p *= t;
  const float e  = __builtin_amdgcn_exp2f(-u * u * 1.4426950408889634f);  // exp(-u^2)
  const float ea = fmaf(-p, e, 1.f);                                      // erf(|u|)
  const float er = __builtin_copysignf(ea, u);
  return fmaf(0.5f * h, er, 0.5f * h);
}

static __device__ __forceinline__ int qi8(float g, float s) {
  return (int)fminf(fmaxf(rintf(g * s), -128.f), 127.f);
}

static __device__ __forceinline__ unsigned q4pack(float4 v, float scl) {
  int q0 = qi8(v.x, scl), q1 = qi8(v.y, scl), q2 = qi8(v.z, scl), q3 = qi8(v.w, scl);
  return (unsigned)(q0 & 255) | ((unsigned)(q1 & 255) << 8) |
         ((unsigned)(q2 & 255) << 16) | ((unsigned)(q3 & 255) << 24);
}

// ---------------- K0a: per-block partial sums of |w| ----------------
__global__ void k_wabs(const float* __restrict__ w1, const float* __restrict__ w2,
                       float* __restrict__ part) {
  const int b = blockIdx.x;
  const float* src = (b < 256 ? w1 : w2) + (size_t)(b & 255) * 4096 + threadIdx.x * 16;
  float s = 0.f;
#pragma unroll
  for (int i = 0; i < 4; ++i) {
    float4 v = *(const float4*)(src + i * 4);
    s += fabsf(v.x) + fabsf(v.y) + fabsf(v.z) + fabsf(v.w);
  }
  __shared__ float red[256];
  red[threadIdx.x] = s;
  __syncthreads();
  for (int off = 128; off > 0; off >>= 1) {
    if (threadIdx.x < (unsigned)off) red[threadIdx.x] += red[threadIdx.x + off];
    __syncthreads();
  }
  if (threadIdx.x == 0) part[b] = red[0];
}

// ---------------- K0b: final mean-abs -> scales ----------------
__global__ void k_wscale(const float* __restrict__ part, float* __restrict__ scales) {
  __shared__ float s1[256], s2[256];
  s1[threadIdx.x] = part[threadIdx.x];
  s2[threadIdx.x] = part[256 + threadIdx.x];
  __syncthreads();
  for (int off = 128; off > 0; off >>= 1) {
    if (threadIdx.x < (unsigned)off) {
      s1[threadIdx.x] += s1[threadIdx.x + off];
      s2[threadIdx.x] += s2[threadIdx.x + off];
    }
    __syncthreads();
  }
  if (threadIdx.x == 0) {
    const float mc1 = fmaxf(s1[0] / 1048576.f, 1e-5f);
    const float mc2 = fmaxf(s2[0] / 1048576.f, 1e-5f);
    scales[0] = mc1; scales[1] = 1.f / mc1;
    scales[2] = mc2; scales[3] = 1.f / mc2;
  }
}

// ---------------- K1: ternary-quantize weights, pack i8 MFMA fragments ----
// frag (nt,ks): lane l holds w[nt*16+(l&15)][ks*64+(l>>4)*16 + j], j=0..15
__global__ void k_pack(const float* __restrict__ w1, const float* __restrict__ w2,
                       const float* __restrict__ scales,
                       signed char* __restrict__ p1, signed char* __restrict__ p2) {
  int slot = blockIdx.x * 256 + threadIdx.x;    // 0..131071 (first 65536 -> p1)
  const bool isw2 = slot >= 65536;
  const float* w = isw2 ? w2 : w1;
  const float scl = isw2 ? scales[3] : scales[1];
  signed char* p = isw2 ? p2 : p1;
  const int K  = isw2 ? HID : DIM;
  const int KS = isw2 ? KS2 : KS1;
  slot &= 65535;
  const int lane = slot & 63;
  const int fr   = slot >> 6;
  const int nt   = fr / KS;
  const int ks   = fr - nt * KS;
  const int n  = nt * 16 + (lane & 15);
  const int k0 = ks * 64 + (lane >> 4) * 16;
  const float* src = w + (size_t)n * K + k0;
  i32x4 outv;
#pragma unroll
  for (int d = 0; d < 4; ++d) {
    unsigned v = 0;
#pragma unroll
    for (int e = 0; e < 4; ++e) {
      int q = (int)fminf(fmaxf(rintf(src[d * 4 + e] * scl), -1.f), 1.f);
      v |= ((unsigned)(q & 255)) << (8 * e);
    }
    outv[d] = (int)v;
  }
  *(i32x4*)(p + (size_t)slot * 16) = outv;
}

// ---------------- K2: fused quant -> GEMM1(i8) -> GELU -> quant -> GEMM2(i8) -> residual
// MT=64, 8 waves. LDS: gbuf 128KB (g halfA bf16 -> qh rows 16..63) + xq 32KB
// (x i8 -> scratch -> qh rows 0..15). g halfB lives in 64 VGPRs/thread.
__global__ __launch_bounds__(512, 2) void k_fused(
    const float* __restrict__ x, const float* __restrict__ b1,
    const float* __restrict__ b2, const signed char* __restrict__ p1,
    const signed char* __restrict__ p2, const float* __restrict__ scales,
    float* __restrict__ out) {
  __shared__ __align__(16) signed char gbuf[131072];
  __shared__ __align__(16) signed char xq[32768];

  float* rxTab = (float*)gbuf;         // [64] recip_x*wsc1 — dead before gA writes
  float* scrP  = (float*)xq;           // [8][64] rowmax partials — after GEMM1
  float* scrS  = scrP + 512;           // [64] 127/mc
  float* scrR  = scrP + 576;           // [64] (mc/127)*wsc2

  const int tid = threadIdx.x;
  const int wv = tid >> 6, ln = tid & 63, lg = ln >> 4, lr = ln & 15;
  const int tok0 = blockIdx.x * MT;
  const float wsc1 = scales[0], wsc2 = scales[2];
  const int swz = (lr & 7) << 4;       // A-row swizzle (row&7 == lr&7)

  // ---- phase 1: load x, per-token absmax int8 quant -> xq (swizzled)
  {
    const int row = tid >> 3, sub = tid & 7;       // 8 threads per 512-float row
    const float4* xr = (const float4*)(x + (size_t)(tok0 + row) * DIM) + sub * 16;
    float4 v[16];
    float am = 0.f;
#pragma unroll
    for (int i = 0; i < 16; ++i) {
      v[i] = xr[i];
      am = fmaxf(am, fmaxf(fmaxf(fabsf(v[i].x), fabsf(v[i].y)),
                           fmaxf(fabsf(v[i].z), fabsf(v[i].w))));
    }
#pragma unroll
    for (int m = 1; m < 8; m <<= 1) am = fmaxf(am, __shfl_xor(am, m));
    const float mc  = fmaxf(am, 1e-5f);
    const float scl = 127.f / mc;
    if (sub == 0) rxTab[row] = mc * (1.f / 127.f) * wsc1;
    const int rswz = (row & 7) << 4;
#pragma unroll
    for (int g16 = 0; g16 < 4; ++g16) {
      u32x4 u;
#pragma unroll
      for (int e = 0; e < 4; ++e) u[e] = q4pack(v[g16 * 4 + e], scl);
      *(u32x4*)&xq[row * DIM + ((sub * 64 + g16 * 16) ^ rswz)] = u;
    }
  }
  __syncthreads();

  float rxw[4][4];
#pragma unroll
  for (int mt = 0; mt < 4; ++mt)
#pragma unroll
    for (int r = 0; r < 4; ++r) rxw[mt][r] = rxTab[mt * 16 + lg * 4 + r];
  __syncthreads();   // all rxTab reads done before gA epilogue writes gbuf

  float hmax[4][4];
#pragma unroll
  for (int mt = 0; mt < 4; ++mt)
#pragma unroll
    for (int r = 0; r < 4; ++r) hmax[mt][r] = 0.f;

  // ---- GEMM1 half B (cols 1024..2047): g kept in regs as packed bf16
  unsigned gB[2][4][4][2];             // [ch][t][mt][pr] — 64 VGPRs
#pragma unroll
  for (int ch = 0; ch < 2; ++ch) {
    i32x4 acc[4][4];
#pragma unroll
    for (int t = 0; t < 4; ++t)
#pragma unroll
      for (int mt = 0; mt < 4; ++mt) acc[t][mt] = (i32x4){0, 0, 0, 0};
#pragma unroll
    for (int ks = 0; ks < KS1; ++ks) {
      i32x4 a[4];
#pragma unroll
      for (int mt = 0; mt < 4; ++mt)
        a[mt] = *(const i32x4*)&xq[(mt * 16 + lr) * DIM + ((ks * 64 + lg * 16) ^ swz)];
#pragma unroll
      for (int t = 0; t < 4; ++t) {
        const int nt = 64 + wv * 8 + ch * 4 + t;
        const i32x4 bfr = *(const i32x4*)(p1 + ((size_t)(nt * KS1 + ks) * 64 + ln) * 16);
#pragma unroll
        for (int mt = 0; mt < 4; ++mt)
          acc[t][mt] = __builtin_amdgcn_mfma_i32_16x16x64_i8(a[mt], bfr, acc[t][mt], 0, 0, 0);
      }
    }
#pragma unroll
    for (int t = 0; t < 4; ++t) {
      const int col = 1024 + wv * 128 + ch * 64 + t * 16 + lr;
      const float bias = b1[col];
#pragma unroll
      for (int mt = 0; mt < 4; ++mt)
#pragma unroll
        for (int pr = 0; pr < 2; ++pr) {
          unsigned v = 0;
#pragma unroll
          for (int hf = 0; hf < 2; ++hf) {
            const int r = pr * 2 + hf;
            const float hv = fmaf((float)acc[t][mt][r], rxw[mt][r], bias);
            const float g  = gelu_erf(hv);
            hmax[mt][r] = fmaxf(hmax[mt][r], fabsf(g));
            v |= ((unsigned)f2bf(g)) << (16 * hf);
          }
          gB[ch][t][mt][pr] = v;
        }
    }
  }

  // ---- GEMM1 half A (cols 0..1023): g -> gbuf as bf16 (swizzled)
#pragma unroll
  for (int ch = 0; ch < 2; ++ch) {
    i32x4 acc[4][4];
#pragma unroll
    for (int t = 0; t < 4; ++t)
#pragma unroll
      for (int mt = 0; mt < 4; ++mt) acc[t][mt] = (i32x4){0, 0, 0, 0};
#pragma unroll
    for (int ks = 0; ks < KS1; ++ks) {
      i32x4 a[4];
#pragma unroll
      for (int mt = 0; mt < 4; ++mt)
        a[mt] = *(const i32x4*)&xq[(mt * 16 + lr) * DIM + ((ks * 64 + lg * 16) ^ swz)];
#pragma unroll
      for (int t = 0; t < 4; ++t) {
        const int nt = wv * 8 + ch * 4 + t;
        const i32x4 bfr = *(const i32x4*)(p1 + ((size_t)(nt * KS1 + ks) * 64 + ln) * 16);
#pragma unroll
        for (int mt = 0; mt < 4; ++mt)
          acc[t][mt] = __builtin_amdgcn_mfma_i32_16x16x64_i8(a[mt], bfr, acc[t][mt], 0, 0, 0);
      }
    }
#pragma unroll
    for (int t = 0; t < 4; ++t) {
      const int col = (wv * 8 + ch * 4 + t) * 16 + lr;
      const float bias = b1[col];
#pragma unroll
      for (int mt = 0; mt < 4; ++mt)
#pragma unroll
        for (int pr = 0; pr < 2; ++pr)
#pragma unroll
          for (int hf = 0; hf < 2; ++hf) {
            const int r = pr * 2 + hf;
            const int row = mt * 16 + lg * 4 + r;
            const float hv = fmaf((float)acc[t][mt][r], rxw[mt][r], bias);
            const float g  = gelu_erf(hv);
            hmax[mt][r] = fmaxf(hmax[mt][r], fabsf(g));
            *(unsigned short*)&gbuf[row * 2048 + ((2 * col) ^ ((row & 7) << 4))] = f2bf(g);
          }
    }
  }
  __syncthreads();   // all xq reads + gA writes done; xq region -> scratch

  // ---- per-token row max across waves
#pragma unroll
  for (int m = 1; m < 16; m <<= 1)
#pragma unroll
    for (int mt = 0; mt < 4; ++mt)
#pragma unroll
      for (int r = 0; r < 4; ++r)
        hmax[mt][r] = fmaxf(hmax[mt][r], __shfl_xor(hmax[mt][r], m));
  if (lr == 0) {
#pragma unroll
    for (int mt = 0; mt < 4; ++mt)
#pragma unroll
      for (int r = 0; r < 4; ++r)
        scrP[wv * 64 + mt * 16 + lg * 4 + r] = hmax[mt][r];
  }
  __syncthreads();
  if (tid < MT) {
    float m = scrP[tid];
#pragma unroll
    for (int w = 1; w < 8; ++w) m = fmaxf(m, scrP[w * 64 + tid]);
    const float mc = fmaxf(m, 1e-5f);
    scrS[tid] = 127.f / mc;
    scrR[tid] = mc * (1.f / 127.f) * wsc2;
  }
  __syncthreads();

  // preload all scales to regs (scratch region is clobbered by quant phase 0)
  float s2w[4][4], r2w[4][4], s2q[4];
#pragma unroll
  for (int mt = 0; mt < 4; ++mt)
#pragma unroll
    for (int r = 0; r < 4; ++r) {
      s2w[mt][r] = scrS[mt * 16 + lg * 4 + r];
      r2w[mt][r] = scrR[mt * 16 + lg * 4 + r];
    }
#pragma unroll
  for (int k = 0; k < 4; ++k) s2q[k] = scrS[k * 16 + (tid >> 5)];
  __syncthreads();

  // ---- 4-phase requantization: {gA LDS, gB regs} -> qh i8 (rows 0..15 in xq
  // region, rows 16..63 in gbuf shifted by -16 rows). Phase k handles rows
  // 16k..16k+15; dst only overwrites gA rows consumed in phase k-1.
#pragma unroll
  for (int k = 0; k < 4; ++k) {
    {  // cols 0..1023 from gA (LDS)
      const int rq  = k * 16 + (tid >> 5);
      const int swr = (rq & 7) << 4;
      const float sA = s2q[k];
      signed char* dst = (k == 0) ? (xq + rq * 2048) : (gbuf + (rq - 16) * 2048);
      const signed char* srow = gbuf + rq * 2048;
#pragma unroll
      for (int i = 0; i < 4; ++i) {
        const int c = (tid & 31) * 8 + i * 256;
        const u32x4 s = *(const u32x4*)&srow[(2 * c) ^ swr];
        unsigned lo = 0, hi = 0;
#pragma unroll
        for (int e = 0; e < 2; ++e) {
          const unsigned w = s[e];
          lo |= ((unsigned)(qi8(bf2f((unsigned short)(w & 0xffff)), sA) & 255)) << (16 * e);
          lo |= ((unsigned)(qi8(bf2f((unsigned short)(w >> 16)), sA) & 255)) << (16 * e + 8);
        }
#pragma unroll
        for (int e = 0; e < 2; ++e) {
          const unsigned w = s[e + 2];
          hi |= ((unsigned)(qi8(bf2f((unsigned short)(w & 0xffff)), sA) & 255)) << (16 * e);
          hi |= ((unsigned)(qi8(bf2f((unsigned short)(w >> 16)), sA) & 255)) << (16 * e + 8);
        }
        u32x2 o; o[0] = lo; o[1] = hi;
        *(u32x2*)&dst[c ^ swr] = o;
      }
    }
    // cols 1024..2047 from gB regs (rows mt=k only)
#pragma unroll
    for (int ch = 0; ch < 2; ++ch)
#pragma unroll
      for (int t = 0; t < 4; ++t) {
        const int col = 1024 + wv * 128 + ch * 64 + t * 16 + lr;
#pragma unroll
        for (int pr = 0; pr < 2; ++pr) {
          const unsigned v = gB[ch][t][k][pr];
#pragma unroll
          for (int hf = 0; hf < 2; ++hf) {
            const int r = pr * 2 + hf;
            const int row = k * 16 + lg * 4 + r;
            const float g = bf2f((unsigned short)(hf ? (v >> 16) : (v & 0xffff)));
            const int q = qi8(g, s2w[k][r]);
            signed char* d2 = (k == 0) ? (xq + row * 2048) : (gbuf + (row - 16) * 2048);
            d2[col ^ ((row & 7) << 4)] = (signed char)q;
          }
        }
      }
    __syncthreads();
  }

  // ---- GEMM2: [64 x 512] i8; wave owns 4 n-tiles
  i32x4 acc2[4][4];
#pragma unroll
  for (int t = 0; t < 4; ++t)
#pragma unroll
    for (int mt = 0; mt < 4; ++mt) acc2[t][mt] = (i32x4){0, 0, 0, 0};
#pragma unroll 8
  for (int ks = 0; ks < KS2; ++ks) {
    i32x4 a[4];
    a[0] = *(const i32x4*)&xq[lr * 2048 + ((ks * 64 + lg * 16) ^ swz)];
#pragma unroll
    for (int mt = 1; mt < 4; ++mt)
      a[mt] = *(const i32x4*)&gbuf[(mt * 16 + lr - 16) * 2048 + ((ks * 64 + lg * 16) ^ swz)];
#pragma unroll
    for (int t = 0; t < 4; ++t) {
      const int nt = wv * 4 + t;
      const i32x4 bfr = *(const i32x4*)(p2 + ((size_t)(nt * KS2 + ks) * 64 + ln) * 16);
#pragma unroll
      for (int mt = 0; mt < 4; ++mt)
        acc2[t][mt] = __builtin_amdgcn_mfma_i32_16x16x64_i8(a[mt], bfr, acc2[t][mt], 0, 0, 0);
    }
  }
#pragma unroll
  for (int t = 0; t < 4; ++t) {
    const int col = (wv * 4 + t) * 16 + lr;
    const float bias = b2[col];
#pragma unroll
    for (int mt = 0; mt < 4; ++mt) {
#pragma unroll
      for (int r = 0; r < 4; ++r) {
        const int row = mt * 16 + lg * 4 + r;
        const size_t gidx = (size_t)(tok0 + row) * DIM + col;
        out[gidx] = fmaf((float)acc2[t][mt][r], r2w[mt][r], bias) + x[gidx];
      }
    }
  }
}

extern "C" void kernel_launch(void* const* d_in, const int* in_sizes, int n_in,
                              void* d_out, int out_size, void* d_ws, size_t ws_size,
                              hipStream_t stream) {
  const float* x  = (const float*)d_in[0];
  const float* w1 = (const float*)d_in[1];
  const float* b1 = (const float*)d_in[2];
  const float* w2 = (const float*)d_in[3];
  const float* b2 = (const float*)d_in[4];
  float* out = (float*)d_out;

  float* wpart   = (float*)d_ws;
  float* wscales = wpart + 512;
  signed char* p1 = (signed char*)((char*)d_ws + 4096);
  signed char* p2 = (signed char*)((char*)d_ws + 4096 + 1048576);

  k_wabs<<<512, 256, 0, stream>>>(w1, w2, wpart);
  k_wscale<<<1, 256, 0, stream>>>(wpart, wscales);
  k_pack<<<512, 256, 0, stream>>>(w1, w2, wscales, p1, p2);
  k_fused<<<1024, 512, 0, stream>>>(x, b1, b2, p1, p2, wscales, out);
}